// Round 13
// baseline (575.491 us; speedup 1.0000x reference)
//
#include <hip/hip_runtime.h>
#include <cstdint>
#include <cstddef>

#define SS 2048
#define CC 3072
#define HDIM 128
#define NH 24

using bf16 = __bf16;
typedef __bf16 bf16x8 __attribute__((ext_vector_type(8)));
typedef float f32x4 __attribute__((ext_vector_type(4)));

typedef const __attribute__((address_space(1))) void* gas1_cvp;
typedef __attribute__((address_space(3))) void* las3_vp;

// async global->LDS, 16B/lane; LDS dest = wave-uniform base + lane*16
__device__ __forceinline__ void gll16(const void* g, void* l) {
  __builtin_amdgcn_global_load_lds((gas1_cvp)g, (las3_vp)l, 16, 0, 0);
}

__device__ __forceinline__ bf16x8 cvt8(f32x4 a, f32x4 b) {
  bf16x8 r;
  r[0] = (bf16)a[0]; r[1] = (bf16)a[1]; r[2] = (bf16)a[2]; r[3] = (bf16)a[3];
  r[4] = (bf16)b[0]; r[5] = (bf16)b[1]; r[6] = (bf16)b[2]; r[7] = (bf16)b[3];
  return r;
}

#define NX ((size_t)SS * CC)        // 6291456
#define NW ((size_t)CC * CC)        // 9437184

// ---------------------------------------------------------------------------
// fp32 -> bf16 bulk convert: z selects {x, wq, wk, wv, wo}; dst contiguous.
// ---------------------------------------------------------------------------
__global__ __launch_bounds__(256)
void k_cvt(const float* __restrict__ s0, const float* __restrict__ s1,
           const float* __restrict__ s2, const float* __restrict__ s3,
           const float* __restrict__ s4, bf16* __restrict__ dst) {
  const int z = blockIdx.y;
  const float* src = (z == 0) ? s0 : (z == 1) ? s1 : (z == 2) ? s2 : (z == 3) ? s3 : s4;
  const size_t nz = (z == 0) ? NX : NW;
  const size_t base = (z == 0) ? 0 : NX + (size_t)(z - 1) * NW;
  const size_t i = ((size_t)blockIdx.x * 256 + threadIdx.x) * 8;
  if (i < nz) {
    const f32x4 a = *(const f32x4*)(src + i);
    const f32x4 b = *(const f32x4*)(src + i + 4);
    *(bf16x8*)(dst + base + i) = cvt8(a, b);
  }
}

// ---------------------------------------------------------------------------
// R11: 256^2-tile QKV GEMM, T4 FIX of R10's regression (191us, MfmaUtil 25%).
// R10's failure: vmcnt(0) at tile-top + loads issued mid-tile = DMA transfer
// + latency serially exposed every tile, with 1 block/CU (128KB LDS) = no
// co-resident block to hide it (m218 lesson: drain-0 ~= unpipelined).
// Fix (T4, same as the R7 attn WIN): issue next tile's 8 gll16 at loop-top
// BEFORE the wait; wait with COUNTED vmcnt(8) ("current tile landed, next
// tile stays in flight"); post-compute barrier for WAR. Ledger: prologue
// t0(8); iter tt: +8 -> 16 outstanding -> vmcnt(8) drains exactly t_tt.
// Everything else identical to R10 (swizzle verified: bank-conflict 1.4e7->0).
// mode 0: out[h][s][d] bf16; mode 1: out[col][row] bf16 (V^T).
// ---------------------------------------------------------------------------
__global__ __launch_bounds__(512, 2)
void k_gemm_qkv_8p(const bf16* __restrict__ xb,
                   const bf16* __restrict__ wqb, const bf16* __restrict__ wkb,
                   const bf16* __restrict__ wvb,
                   const float* __restrict__ bq, const float* __restrict__ bk,
                   const float* __restrict__ bv,
                   bf16* __restrict__ Qo, bf16* __restrict__ Ko, bf16* __restrict__ Vo) {
  const int z = blockIdx.z;
  const bf16* W   = (z == 0) ? wqb : (z == 1) ? wkb : wvb;
  const float* Bi = (z == 0) ? bq : (z == 1) ? bk : bv;
  const int mode  = (z == 2) ? 1 : 0;
  void* out       = (z == 0) ? (void*)Qo : (z == 1) ? (void*)Ko : (void*)Vo;

  __shared__ __align__(16) bf16 As[2][256][64];  // 64KB
  __shared__ __align__(16) bf16 Ws[2][256][64];  // 64KB
  const int t = threadIdx.x, wave = t >> 6, lane = t & 63;
  const int m0 = blockIdx.y * 256, n0 = blockIdx.x * 256;
  const int wm = (wave >> 2) * 128, wn = (wave & 3) * 64;
  const int fr = lane & 15, g4 = lane >> 4;
  const int K = CC, M = SS;

  // chunk c (0..31) = rows 8c..8c+7 of a [256][64] tile (1KB, linear dest).
  // lane: row = 8c + l/8, linear slot l&7 holds col-block (l&7)^(row&7).
  auto stage = [&](int buf, int k0, int i) {
    const int c = wave * 4 + i;
    const int row = c * 8 + (lane >> 3);
    const int sl = (lane & 7) ^ (row & 7);
    gll16(xb + (size_t)(m0 + row) * K + k0 + sl * 8,
          (char*)&As[buf][0][0] + c * 1024);
    gll16(W + (size_t)(n0 + row) * K + k0 + sl * 8,
          (char*)&Ws[buf][0][0] + c * 1024);
  };

  f32x4 acc[8][4] = {};

  stage(0, 0, 0); stage(0, 0, 1); stage(0, 0, 2); stage(0, 0, 3);  // t0: 8 in flight

  const int NT = K / 64;  // 48
  for (int tt = 0; tt < NT; ++tt) {
    const int buf = tt & 1;
    // T4: prefetch next tile FIRST, then counted wait (never 0 mid-loop).
    if (tt + 1 < NT) {
      const int nk = (tt + 1) * 64;
      stage(buf ^ 1, nk, 0); stage(buf ^ 1, nk, 1);
      stage(buf ^ 1, nk, 2); stage(buf ^ 1, nk, 3);
      asm volatile("s_waitcnt vmcnt(8)" ::: "memory");  // cur tile landed; next stays in flight
    } else {
      asm volatile("s_waitcnt vmcnt(0)" ::: "memory");  // last tile: nothing else outstanding
    }
    __builtin_amdgcn_s_barrier();
    __builtin_amdgcn_sched_barrier(0);

    // B-fragments: register-cached for all 4 phases (8 ds_read_b128)
    bf16x8 bfr[4][2];
#pragma unroll
    for (int ni = 0; ni < 4; ++ni)
#pragma unroll
      for (int kk = 0; kk < 2; ++kk) {
        const int row = wn + ni * 16 + fr;
        const int sl = (kk * 4 + g4) ^ (row & 7);
        bfr[ni][kk] = *(const bf16x8*)((const char*)&Ws[buf][0][0] + row * 128 + sl * 16);
      }

#pragma unroll
    for (int ph = 0; ph < 4; ++ph) {
      bf16x8 am[2][2];
#pragma unroll
      for (int mi2 = 0; mi2 < 2; ++mi2)
#pragma unroll
        for (int kk = 0; kk < 2; ++kk) {
          const int row = wm + (ph * 2 + mi2) * 16 + fr;
          const int sl = (kk * 4 + g4) ^ (row & 7);
          am[mi2][kk] = *(const bf16x8*)((const char*)&As[buf][0][0] + row * 128 + sl * 16);
        }
      __builtin_amdgcn_s_setprio(1);
#pragma unroll
      for (int kk = 0; kk < 2; ++kk)
#pragma unroll
        for (int mi2 = 0; mi2 < 2; ++mi2)
#pragma unroll
          for (int ni = 0; ni < 4; ++ni)
            acc[ph * 2 + mi2][ni] = __builtin_amdgcn_mfma_f32_16x16x32_bf16(
                am[mi2][kk], bfr[ni][kk], acc[ph * 2 + mi2][ni], 0, 0, 0);
      __builtin_amdgcn_s_setprio(0);
    }

    __builtin_amdgcn_s_barrier();   // WAR: all waves done reading buf before next stage
    __builtin_amdgcn_sched_barrier(0);
  }

  const int lr4 = g4 * 4;
#pragma unroll
  for (int mi = 0; mi < 8; ++mi)
#pragma unroll
    for (int ni = 0; ni < 4; ++ni) {
      const int col = n0 + wn + ni * 16 + fr;
      const float bb = Bi[col];
#pragma unroll
      for (int r = 0; r < 4; ++r) {
        const int row = m0 + wm + mi * 16 + lr4 + r;
        const float v = acc[mi][ni][r] + bb;
        if (mode == 0)
          ((bf16*)out)[((size_t)(col >> 7) * M + row) * 128 + (col & 127)] = (bf16)v;
        else
          ((bf16*)out)[(size_t)col * M + row] = (bf16)v;
      }
    }
}

// ---------------------------------------------------------------------------
// Pure-bf16 bt-GEMM, BK=64, plane-split LDS (kept for the out-projection:
// its 96-block 256^2 grid would under-fill the chip; 128^2 = 384 blocks).
// mode 2: out[row][col] fp32 (final output).
// ---------------------------------------------------------------------------
__device__ __forceinline__ void gemm_bt_bf16(const bf16* __restrict__ A,
                                             const bf16* __restrict__ W,
                                             const float* __restrict__ bias,
                                             void* __restrict__ out,
                                             int M, int N, int K, int mode) {
  __shared__ __align__(16) bf16 As[2][128][32];  // [k-plane][row][32] 16KB
  __shared__ __align__(16) bf16 Ws[2][128][32];  // 16KB
  const int t = threadIdx.x, wave = t >> 6, lane = t & 63;
  const int m0 = blockIdx.y * 128, n0 = blockIdx.x * 128;
  const int wm = (wave >> 1) * 64, wn = (wave & 1) * 64;
  const int fr = lane & 15, fq = (lane >> 4) * 8;

  f32x4 acc[4][4] = {};

  for (int k0 = 0; k0 < K; k0 += 64) {
    __syncthreads();
#pragma unroll
    for (int it = 0; it < 4; ++it) {
      const int pc = wave * 4 + it;          // 1KB chunk id 0..15, wave-uniform
      const int pl = pc >> 3, rb = pc & 7;   // k-plane, 16-row block
      const int row = rb * 16 + (lane >> 2);
      const int c8 = (lane & 3) * 8;
      gll16(A + (size_t)(m0 + row) * K + k0 + pl * 32 + c8,
            (char*)&As[0][0][0] + pc * 1024);
      gll16(W + (size_t)(n0 + row) * K + k0 + pl * 32 + c8,
            (char*)&Ws[0][0][0] + pc * 1024);
    }
    __syncthreads();
#pragma unroll
    for (int c = 0; c < 2; ++c) {
      bf16x8 a[4], b[4];
#pragma unroll
      for (int i = 0; i < 4; ++i) a[i] = *(const bf16x8*)&As[c][wm + i * 16 + fr][fq];
#pragma unroll
      for (int j = 0; j < 4; ++j) b[j] = *(const bf16x8*)&Ws[c][wn + j * 16 + fr][fq];
#pragma unroll
      for (int i = 0; i < 4; ++i)
#pragma unroll
        for (int j = 0; j < 4; ++j)
          acc[i][j] = __builtin_amdgcn_mfma_f32_16x16x32_bf16(a[i], b[j], acc[i][j], 0, 0, 0);
    }
  }

  const int lr4 = (lane >> 4) * 4;
#pragma unroll
  for (int i = 0; i < 4; ++i) {
#pragma unroll
    for (int j = 0; j < 4; ++j) {
      const int col = n0 + wn + j * 16 + fr;
      const float bb = bias[col];
#pragma unroll
      for (int r = 0; r < 4; ++r) {
        const int row = m0 + wm + i * 16 + lr4 + r;
        const float v = acc[i][j][r] + bb;
        if (mode == 0)
          ((bf16*)out)[((size_t)(col >> 7) * M + row) * 128 + (col & 127)] = (bf16)v;
        else if (mode == 1)
          ((bf16*)out)[(size_t)col * M + row] = (bf16)v;
        else
          ((float*)out)[(size_t)row * N + col] = v;
      }
    }
  }
}

__global__ __launch_bounds__(256, 4)
void k_gemm_out_b(const bf16* __restrict__ A, const bf16* __restrict__ wob,
                  const float* __restrict__ bo, float* __restrict__ out) {
  gemm_bt_bf16(A, wob, bo, out, SS, CC, CC, 2);
}

// ---------------------------------------------------------------------------
// Fallback (ws too small): fp32-staging GEMM (round-4 structure).
// ---------------------------------------------------------------------------
template<int AF32>
__device__ __forceinline__ void gemm_core(const void* __restrict__ Ap,
                                          const float* __restrict__ W,
                                          const float* __restrict__ bias,
                                          void* __restrict__ out,
                                          int M, int N, int K, int mode) {
  __shared__ __align__(16) bf16 As[128][32];
  __shared__ __align__(16) bf16 Ws[128][32];
  const int t = threadIdx.x, wave = t >> 6, lane = t & 63;
  const int m0 = blockIdx.y * 128, n0 = blockIdx.x * 128;
  const int wm = (wave >> 1) * 64, wn = (wave & 1) * 64;
  const int fr = lane & 15, fq = (lane >> 4) * 8;
  const int pi0 = wave * 128 + lane;
  const int pi1 = pi0 + 64;
  const int row0 = pi0 >> 2, c0 = (pi0 & 3) * 8;
  const int row1 = pi1 >> 2, c1 = (pi1 & 3) * 8;

  f32x4 raf0[2], raf1[2], rw0[2], rw1[2];
  bf16x8 rab0, rab1;

  auto issue = [&](int k0) {
    if (AF32) {
      const float* A = (const float*)Ap;
      const float* p0 = A + (size_t)(m0 + row0) * K + k0 + c0;
      raf0[0] = *(const f32x4*)p0; raf0[1] = *(const f32x4*)(p0 + 4);
      const float* p1 = A + (size_t)(m0 + row1) * K + k0 + c1;
      raf1[0] = *(const f32x4*)p1; raf1[1] = *(const f32x4*)(p1 + 4);
    } else {
      const bf16* A = (const bf16*)Ap;
      rab0 = *(const bf16x8*)(A + (size_t)(m0 + row0) * K + k0 + c0);
      rab1 = *(const bf16x8*)(A + (size_t)(m0 + row1) * K + k0 + c1);
    }
    const float* q0 = W + (size_t)(n0 + row0) * K + k0 + c0;
    rw0[0] = *(const f32x4*)q0; rw0[1] = *(const f32x4*)(q0 + 4);
    const float* q1 = W + (size_t)(n0 + row1) * K + k0 + c1;
    rw1[0] = *(const f32x4*)q1; rw1[1] = *(const f32x4*)(q1 + 4);
  };

  f32x4 acc[4][4] = {};
  issue(0);
  for (int k0 = 0; k0 < K; k0 += 32) {
    __syncthreads();
    if (AF32) {
      *(bf16x8*)&As[row0][c0] = cvt8(raf0[0], raf0[1]);
      *(bf16x8*)&As[row1][c1] = cvt8(raf1[0], raf1[1]);
    } else {
      *(bf16x8*)&As[row0][c0] = rab0;
      *(bf16x8*)&As[row1][c1] = rab1;
    }
    *(bf16x8*)&Ws[row0][c0] = cvt8(rw0[0], rw0[1]);
    *(bf16x8*)&Ws[row1][c1] = cvt8(rw1[0], rw1[1]);
    __syncthreads();
    if (k0 + 32 < K) issue(k0 + 32);
    bf16x8 a[4], b[4];
#pragma unroll
    for (int i = 0; i < 4; ++i) a[i] = *(const bf16x8*)&As[wm + i * 16 + fr][fq];
#pragma unroll
    for (int j = 0; j < 4; ++j) b[j] = *(const bf16x8*)&Ws[wn + j * 16 + fr][fq];
#pragma unroll
    for (int i = 0; i < 4; ++i)
#pragma unroll
      for (int j = 0; j < 4; ++j)
        acc[i][j] = __builtin_amdgcn_mfma_f32_16x16x32_bf16(a[i], b[j], acc[i][j], 0, 0, 0);
  }

  const int lr4 = (lane >> 4) * 4;
#pragma unroll
  for (int i = 0; i < 4; ++i) {
#pragma unroll
    for (int j = 0; j < 4; ++j) {
      const int col = n0 + wn + j * 16 + fr;
      const float bb = bias[col];
#pragma unroll
      for (int r = 0; r < 4; ++r) {
        const int row = m0 + wm + i * 16 + lr4 + r;
        const float v = acc[i][j][r] + bb;
        if (mode == 0)
          ((bf16*)out)[((size_t)(col >> 7) * M + row) * 128 + (col & 127)] = (bf16)v;
        else if (mode == 1)
          ((bf16*)out)[(size_t)col * M + row] = (bf16)v;
        else
          ((float*)out)[(size_t)row * N + col] = v;
      }
    }
  }
}

__global__ __launch_bounds__(256, 2)
void k_gemm_qkv_f(const float* __restrict__ x,
                  const float* __restrict__ wq, const float* __restrict__ wk,
                  const float* __restrict__ wv,
                  const float* __restrict__ bq, const float* __restrict__ bk,
                  const float* __restrict__ bv,
                  bf16* __restrict__ Qo, bf16* __restrict__ Ko, bf16* __restrict__ Vo) {
  const int z = blockIdx.z;
  const float* W = (z == 0) ? wq : (z == 1) ? wk : wv;
  const float* B = (z == 0) ? bq : (z == 1) ? bk : bv;
  void* O        = (z == 0) ? (void*)Qo : (z == 1) ? (void*)Ko : (void*)Vo;
  gemm_core<1>(x, W, B, O, SS, CC, CC, (z == 2) ? 1 : 0);
}

__global__ __launch_bounds__(256, 2)
void k_gemm_out_f(const bf16* __restrict__ A, const float* __restrict__ wo,
                  const float* __restrict__ bo, float* __restrict__ out) {
  gemm_core<0>(A, wo, bo, out, SS, CC, CC, 2);
}

// ---------------------------------------------------------------------------
// RMSNorm + RoPE in place on Q,K ([H][S][HD] bf16); Q gets 1/sqrt(HD)*log2e
// folded in. One wave per (s,h); lane L owns elements 2L, 2L+1.
// ---------------------------------------------------------------------------
__global__ __launch_bounds__(256)
void k_norm_rope(bf16* __restrict__ Q, bf16* __restrict__ K,
                 const float* __restrict__ rope,
                 const float* __restrict__ qw, const float* __restrict__ kw) {
  const int t = threadIdx.x, wave = t >> 6, lane = t & 63;
  const int idx = blockIdx.x * 4 + wave;
  const int s = idx / NH, h = idx % NH;
  const size_t base = ((size_t)h * SS + s) * HDIM + 2 * lane;

  bf16 q2[2], k2[2];
  *(uint32_t*)q2 = *(const uint32_t*)(Q + base);
  *(uint32_t*)k2 = *(const uint32_t*)(K + base);
  const float q0 = (float)q2[0], q1 = (float)q2[1];
  const float k0 = (float)k2[0], k1 = (float)k2[1];
  float sq = q0 * q0 + q1 * q1;
  float sk = k0 * k0 + k1 * k1;
#pragma unroll
  for (int m = 1; m < 64; m <<= 1) {
    sq += __shfl_xor(sq, m);
    sk += __shfl_xor(sk, m);
  }
  const float rq = rsqrtf(sq * (1.0f / 128.0f) + 1e-6f);
  const float rk = rsqrtf(sk * (1.0f / 128.0f) + 1e-6f);

  const float qn0 = q0 * rq * qw[2 * lane], qn1 = q1 * rq * qw[2 * lane + 1];
  const float kn0 = k0 * rk * kw[2 * lane], kn1 = k1 * rk * kw[2 * lane + 1];

  const f32x4 rp = *(const f32x4*)(rope + (size_t)s * 256 + 4 * lane);
  const float r00 = rp[0], r01 = rp[1], r10 = rp[2], r11 = rp[3];

  const float SC = 0.08838834764831845f * 1.44269504088896340f;  // 1/sqrt(128)*log2e
  const float oq0 = (r00 * qn0 + r01 * qn1) * SC;
  const float oq1 = (r10 * qn0 + r11 * qn1) * SC;
  const float ok0 = r00 * kn0 + r01 * kn1;
  const float ok1 = r10 * kn0 + r11 * kn1;

  bf16 wq2[2] = {(bf16)oq0, (bf16)oq1};
  bf16 wk2[2] = {(bf16)ok0, (bf16)ok1};
  *(uint32_t*)(Q + base) = *(uint32_t*)wq2;
  *(uint32_t*)(K + base) = *(uint32_t*)wk2;
}

// ---------------------------------------------------------------------------
// Flash attention, fixed-max softmax (exp2 domain, constant M=32).
// R7 pipelined staging (measured WIN, 524->509): Ks double-buffered, counted
// vmcnt (16/8), raw s_barrier, never vmcnt(0) in steady state. In-register P
// via swapped QK^T + kpos-permuted K staging (R5). Kept as-is.
// ---------------------------------------------------------------------------
__global__ __launch_bounds__(128, 2)
void k_attn(const bf16* __restrict__ Q, const bf16* __restrict__ Kt,
            const bf16* __restrict__ Vt, bf16* __restrict__ Out) {
  __shared__ __align__(16) bf16 Ks[2][64][128];  // dbuf: slot x d (kpos-perm) 32KB
  __shared__ __align__(16) bf16 Vs[128][64];     // d x kpos                   16KB
  const int t = threadIdx.x, wave = t >> 6, lane = t & 63;
  const int bx = blockIdx.x;               // 0..767
  const int xg = bx & 7, slot = bx >> 3;   // xcd-group, slot 0..95
  const int h = xg * 3 + (slot >> 5);      // 3 heads per xcd-group
  const int q0 = (slot & 31) * 64;
  const int fr = lane & 15, fq = (lane >> 4) * 8;
  const int g4 = lane >> 4;                // 16B-slot group 0..3
  const int wq0 = wave * 32;               // this wave's 32-row q window
  const float FM = 32.0f;  // fixed softmax max (log2 domain)

  // Q fragments for both 16-row tiles (B operand of swapped QK^T)
  bf16x8 aq[2][4];
#pragma unroll
  for (int qt = 0; qt < 2; ++qt)
#pragma unroll
    for (int kc = 0; kc < 4; ++kc)
      aq[qt][kc] = *(const bf16x8*)(
          Q + ((size_t)h * SS + q0 + wq0 + qt * 16 + fr) * HDIM + kc * 32 + fq);

  // staging lambdas: 8 x 1KB chunks per wave each (K tile 16KB, V tile 16KB)
  auto stageK = [&](int buf, int k0) {
#pragma unroll
    for (int it = 0; it < 8; ++it) {
      const int pc = wave * 8 + it;
      const int s  = pc * 4 + (lane >> 4);
      const int kp = 32 * ((s >> 4) & 1) + 8 * ((s >> 2) & 3)
                   + 4 * (s >> 5) + (s & 3);
      const int sl = (lane & 15) ^ (s & 7);
      gll16(Kt + ((size_t)h * SS + k0 + kp) * HDIM + sl * 8,
            (char*)&Ks[buf][0][0] + pc * 1024);
    }
  };
  auto stageV = [&](int k0) {
#pragma unroll
    for (int it = 0; it < 8; ++it) {
      const int pc = wave * 8 + it;
      const int d  = pc * 8 + (lane >> 3);
      const int sl = (lane & 7) ^ (d & 7);
      gll16(Vt + ((size_t)h * HDIM + d) * SS + k0 + sl * 8,
            (char*)&Vs[0][0] + pc * 1024);
    }
  };

  f32x4 oacc[2][8] = {};
  float lacc[2] = {0.f, 0.f};

  stageK(0, 0);  // prologue: K for step 0 in flight
  int cur = 0;

  for (int k0 = 0; k0 < SS; k0 += 64) {
    const bool notlast = (k0 + 64 < SS);
    stageV(k0);                       // V for THIS step (hides under QK+softmax)
    if (notlast) {
      stageK(cur ^ 1, k0 + 64);       // K for NEXT step (hides under this whole step)
      asm volatile("s_waitcnt vmcnt(16)" ::: "memory");  // K-cur landed (V+Knext in flight)
    } else {
      asm volatile("s_waitcnt vmcnt(8)" ::: "memory");   // K-cur landed (V in flight)
    }
    __builtin_amdgcn_s_barrier();
    __builtin_amdgcn_sched_barrier(0);

    // S^T tiles: mfma(A=K, B=Q) on Ks[cur]. Lane (fr,g4), reg r:
    // pv[jt][r] = P[qrow=fr][kpos = 32*(jt&1) + 8*g4 + 4*(jt>>1) + r].
    f32x4 sacc[2][4] = {};
#pragma unroll
    for (int kc = 0; kc < 4; ++kc) {
#pragma unroll
      for (int jt = 0; jt < 4; ++jt) {
        const bf16x8 b =
            *(const bf16x8*)&Ks[cur][jt * 16 + fr][((((kc << 2) + g4) ^ (fr & 7)) << 3)];
        sacc[0][jt] = __builtin_amdgcn_mfma_f32_16x16x32_bf16(b, aq[0][kc], sacc[0][jt], 0, 0, 0);
        sacc[1][jt] = __builtin_amdgcn_mfma_f32_16x16x32_bf16(b, aq[1][kc], sacc[1][jt], 0, 0, 0);
      }
    }

    // softmax in-register (no LDS) — overlaps V's in-flight loads.
    // ap[kc][j] = pv[2*(j>>2)+kc][j&3]  (kpos = 32*kc + 8*g4 + j)
    bf16x8 ap[2][2];
#pragma unroll
    for (int qt = 0; qt < 2; ++qt) {
      float pv[4][4];
      float ps = 0.f;
#pragma unroll
      for (int jt = 0; jt < 4; ++jt)
#pragma unroll
        for (int r = 0; r < 4; ++r) {
          pv[jt][r] = exp2f(sacc[qt][jt][r] - FM);
          ps += pv[jt][r];
        }
      lacc[qt] += ps;
#pragma unroll
      for (int kc = 0; kc < 2; ++kc) {
        bf16x8 a;
        a[0] = (bf16)pv[kc][0];     a[1] = (bf16)pv[kc][1];
        a[2] = (bf16)pv[kc][2];     a[3] = (bf16)pv[kc][3];
        a[4] = (bf16)pv[2 + kc][0]; a[5] = (bf16)pv[2 + kc][1];
        a[6] = (bf16)pv[2 + kc][2]; a[7] = (bf16)pv[2 + kc][3];
        ap[qt][kc] = a;
      }
    }

    if (notlast) {
      asm volatile("s_waitcnt vmcnt(8)" ::: "memory");   // V landed (Knext in flight)
    } else {
      asm volatile("s_waitcnt vmcnt(0)" ::: "memory");   // V landed (nothing else)
    }
    __builtin_amdgcn_s_barrier();
    __builtin_amdgcn_sched_barrier(0);

    // O += P V
#pragma unroll
    for (int kc = 0; kc < 2; ++kc) {
#pragma unroll
      for (int jd = 0; jd < 8; ++jd) {
        const int d = jd * 16 + fr;
        const bf16x8 b =
            *(const bf16x8*)&Vs[d][((((kc << 2) + g4) ^ (fr & 7)) << 3)];
        oacc[0][jd] = __builtin_amdgcn_mfma_f32_16x16x32_bf16(ap[0][kc], b, oacc[0][jd], 0, 0, 0);
        oacc[1][jd] = __builtin_amdgcn_mfma_f32_16x16x32_bf16(ap[1][kc], b, oacc[1][jd], 0, 0, 0);
      }
    }

    __builtin_amdgcn_s_barrier();   // WAR: all waves done reading Vs / Ks[cur]
    __builtin_amdgcn_sched_barrier(0);
    cur ^= 1;
  }

  // l[qrow=fr]: reduce partials over g4 (xor16/32), then broadcast to the
  // lanes that hold qrow = g4*4+r in the O epilogue (width-16 shfl).
#pragma unroll
  for (int qt = 0; qt < 2; ++qt) {
    float l = lacc[qt];
    l += __shfl_xor(l, 16);
    l += __shfl_xor(l, 32);
    const float linv = 1.0f / l;
#pragma unroll
    for (int r = 0; r < 4; ++r) {
      const float inv = __shfl(linv, g4 * 4 + r, 16);
      const int row = q0 + wq0 + qt * 16 + g4 * 4 + r;
#pragma unroll
      for (int jd = 0; jd < 8; ++jd) {
        const int col = h * HDIM + jd * 16 + fr;
        Out[(size_t)row * CC + col] = (bf16)(oacc[qt][jd][r] * inv);
      }
    }
  }
}

// ---------------------------------------------------------------------------
extern "C" void kernel_launch(void* const* d_in, const int* in_sizes, int n_in,
                              void* d_out, int out_size, void* d_ws, size_t ws_size,
                              hipStream_t stream) {
  const float* x    = (const float*)d_in[0];
  const float* rope = (const float*)d_in[1];
  const float* wq   = (const float*)d_in[2];
  const float* bq   = (const float*)d_in[3];
  const float* wk   = (const float*)d_in[4];
  const float* bk   = (const float*)d_in[5];
  const float* wv   = (const float*)d_in[6];
  const float* bv   = (const float*)d_in[7];
  const float* wo   = (const float*)d_in[8];
  const float* bo   = (const float*)d_in[9];
  const float* qw   = (const float*)d_in[10];
  const float* kw   = (const float*)d_in[11];

  const size_t need = (4 * NX + 4 * NW) * sizeof(bf16);
  bf16* Vt = (bf16*)d_out;  // d_out doubles as V^T scratch until final GEMM

  if (ws_size >= need) {
    bf16* xb  = (bf16*)d_ws;
    bf16* wqb = xb + NX;
    bf16* wkb = wqb + NW;
    bf16* wvb = wkb + NW;
    bf16* wob = wvb + NW;
    bf16* Qn  = wob + NW;
    bf16* Kn  = Qn + NX;
    bf16* Ao  = Kn + NX;

    k_cvt<<<dim3((unsigned)(NW / 2048), 5), 256, 0, stream>>>(x, wq, wk, wv, wo, xb);
    k_gemm_qkv_8p<<<dim3(CC / 256, SS / 256, 3), 512, 0, stream>>>(
        xb, wqb, wkb, wvb, bq, bk, bv, Qn, Kn, Vt);
    k_norm_rope<<<dim3(SS * NH / 4), 256, 0, stream>>>(Qn, Kn, rope, qw, kw);
    k_attn<<<dim3((SS / 64) * NH), 128, 0, stream>>>(Qn, Kn, Vt, Ao);
    k_gemm_out_b<<<dim3(CC / 128, SS / 128), 256, 0, stream>>>(Ao, wob, bo, (float*)d_out);
  } else {
    bf16* Qn = (bf16*)d_ws;
    bf16* Kn = Qn + NX;
    bf16* Ao = Kn + NX;

    k_gemm_qkv_f<<<dim3(CC / 128, SS / 128, 3), 256, 0, stream>>>(
        x, wq, wk, wv, bq, bk, bv, Qn, Kn, Vt);
    k_norm_rope<<<dim3(SS * NH / 4), 256, 0, stream>>>(Qn, Kn, rope, qw, kw);
    k_attn<<<dim3((SS / 64) * NH), 128, 0, stream>>>(Qn, Kn, Vt, Ao);
    k_gemm_out_f<<<dim3(CC / 128, SS / 128), 256, 0, stream>>>(Ao, wo, bo, (float*)d_out);
  }
}

// Round 14
// 523.380 us; speedup vs baseline: 1.0996x; 1.0996x over previous
//
#include <hip/hip_runtime.h>
#include <cstdint>
#include <cstddef>

#define SS 2048
#define CC 3072
#define HDIM 128
#define NH 24

using bf16 = __bf16;
typedef __bf16 bf16x8 __attribute__((ext_vector_type(8)));
typedef float f32x4 __attribute__((ext_vector_type(4)));

typedef const __attribute__((address_space(1))) void* gas1_cvp;
typedef __attribute__((address_space(3))) void* las3_vp;

// async global->LDS, 16B/lane; LDS dest = wave-uniform base + lane*16
__device__ __forceinline__ void gll16(const void* g, void* l) {
  __builtin_amdgcn_global_load_lds((gas1_cvp)g, (las3_vp)l, 16, 0, 0);
}

__device__ __forceinline__ bf16x8 cvt8(f32x4 a, f32x4 b) {
  bf16x8 r;
  r[0] = (bf16)a[0]; r[1] = (bf16)a[1]; r[2] = (bf16)a[2]; r[3] = (bf16)a[3];
  r[4] = (bf16)b[0]; r[5] = (bf16)b[1]; r[6] = (bf16)b[2]; r[7] = (bf16)b[3];
  return r;
}

#define NX ((size_t)SS * CC)        // 6291456
#define NW ((size_t)CC * CC)        // 9437184

// ---------------------------------------------------------------------------
// fp32 -> bf16 bulk convert: z selects {x, wq, wk, wv, wo}; dst contiguous.
// ---------------------------------------------------------------------------
__global__ __launch_bounds__(256)
void k_cvt(const float* __restrict__ s0, const float* __restrict__ s1,
           const float* __restrict__ s2, const float* __restrict__ s3,
           const float* __restrict__ s4, bf16* __restrict__ dst) {
  const int z = blockIdx.y;
  const float* src = (z == 0) ? s0 : (z == 1) ? s1 : (z == 2) ? s2 : (z == 3) ? s3 : s4;
  const size_t nz = (z == 0) ? NX : NW;
  const size_t base = (z == 0) ? 0 : NX + (size_t)(z - 1) * NW;
  const size_t i = ((size_t)blockIdx.x * 256 + threadIdx.x) * 8;
  if (i < nz) {
    const f32x4 a = *(const f32x4*)(src + i);
    const f32x4 b = *(const f32x4*)(src + i + 4);
    *(bf16x8*)(dst + base + i) = cvt8(a, b);
  }
}

// ---------------------------------------------------------------------------
// Pure-bf16 bt-GEMM, BK=64 (32 MFMA per barrier pair), plane-split LDS.
// REVERTED to the 128^2 4-blocks/CU structure (R10 config, measured 508.9us;
// the 256^2 fine-phase experiment lost both ways: 191us drain-0 / 222us
// counted-vmcnt — 288-block tail @1 block/CU is structural).
// R13 add: T1 bijective XCD swizzle via explicit tile coords (tx,ty).
// mode 0: out[h][s][d] bf16; mode 1: out[col][row] bf16 (V^T);
// mode 2: out[row][col] fp32 (final output).
// ---------------------------------------------------------------------------
__device__ __forceinline__ void gemm_bt_bf16(const bf16* __restrict__ A,
                                             const bf16* __restrict__ W,
                                             const float* __restrict__ bias,
                                             void* __restrict__ out,
                                             int M, int N, int K, int mode,
                                             int tx, int ty) {
  __shared__ __align__(16) bf16 As[2][128][32];  // [k-plane][row][32] 16KB
  __shared__ __align__(16) bf16 Ws[2][128][32];  // 16KB
  const int t = threadIdx.x, wave = t >> 6, lane = t & 63;
  const int m0 = ty * 128, n0 = tx * 128;
  const int wm = (wave >> 1) * 64, wn = (wave & 1) * 64;
  const int fr = lane & 15, fq = (lane >> 4) * 8;

  f32x4 acc[4][4] = {};

  for (int k0 = 0; k0 < K; k0 += 64) {
    __syncthreads();
#pragma unroll
    for (int it = 0; it < 4; ++it) {
      const int pc = wave * 4 + it;          // 1KB chunk id 0..15, wave-uniform
      const int pl = pc >> 3, rb = pc & 7;   // k-plane, 16-row block
      const int row = rb * 16 + (lane >> 2);
      const int c8 = (lane & 3) * 8;
      gll16(A + (size_t)(m0 + row) * K + k0 + pl * 32 + c8,
            (char*)&As[0][0][0] + pc * 1024);
      gll16(W + (size_t)(n0 + row) * K + k0 + pl * 32 + c8,
            (char*)&Ws[0][0][0] + pc * 1024);
    }
    __syncthreads();
#pragma unroll
    for (int c = 0; c < 2; ++c) {
      bf16x8 a[4], b[4];
#pragma unroll
      for (int i = 0; i < 4; ++i) a[i] = *(const bf16x8*)&As[c][wm + i * 16 + fr][fq];
#pragma unroll
      for (int j = 0; j < 4; ++j) b[j] = *(const bf16x8*)&Ws[c][wn + j * 16 + fr][fq];
#pragma unroll
      for (int i = 0; i < 4; ++i)
#pragma unroll
        for (int j = 0; j < 4; ++j)
          acc[i][j] = __builtin_amdgcn_mfma_f32_16x16x32_bf16(a[i], b[j], acc[i][j], 0, 0, 0);
    }
  }

  const int lr4 = (lane >> 4) * 4;
#pragma unroll
  for (int i = 0; i < 4; ++i) {
#pragma unroll
    for (int j = 0; j < 4; ++j) {
      const int col = n0 + wn + j * 16 + fr;
      const float bb = bias[col];
#pragma unroll
      for (int r = 0; r < 4; ++r) {
        const int row = m0 + wm + i * 16 + lr4 + r;
        const float v = acc[i][j][r] + bb;
        if (mode == 0)
          ((bf16*)out)[((size_t)(col >> 7) * M + row) * 128 + (col & 127)] = (bf16)v;
        else if (mode == 1)
          ((bf16*)out)[(size_t)col * M + row] = (bf16)v;
        else
          ((float*)out)[(size_t)row * N + col] = v;
      }
    }
  }
}

// T1 bijective XCD swizzle for a 24x16 = 384-block (x,y) grid (384 % 8 == 0):
// flat' = (flat%8)*48 + flat/8 -> XCD c owns a contiguous 48-tile band
// (2 full A-row panels, L2-resident) instead of scattered rows.
__device__ __forceinline__ void xcd_swz24x16(int& tx, int& ty) {
  const int flat = ty * 24 + tx;
  const int swz = (flat & 7) * 48 + (flat >> 3);
  tx = swz % 24;
  ty = swz / 24;
}

__global__ __launch_bounds__(256, 4)
void k_gemm_qkv_b(const bf16* __restrict__ xb,
                  const bf16* __restrict__ wqb, const bf16* __restrict__ wkb,
                  const bf16* __restrict__ wvb,
                  const float* __restrict__ bq, const float* __restrict__ bk,
                  const float* __restrict__ bv,
                  bf16* __restrict__ Qo, bf16* __restrict__ Ko, bf16* __restrict__ Vo) {
  const int z = blockIdx.z;
  const bf16* W  = (z == 0) ? wqb : (z == 1) ? wkb : wvb;
  const float* B = (z == 0) ? bq : (z == 1) ? bk : bv;
  void* O        = (z == 0) ? (void*)Qo : (z == 1) ? (void*)Ko : (void*)Vo;
  int tx = blockIdx.x, ty = blockIdx.y;
  xcd_swz24x16(tx, ty);
  gemm_bt_bf16(xb, W, B, O, SS, CC, CC, (z == 2) ? 1 : 0, tx, ty);
}

__global__ __launch_bounds__(256, 4)
void k_gemm_out_b(const bf16* __restrict__ A, const bf16* __restrict__ wob,
                  const float* __restrict__ bo, float* __restrict__ out) {
  int tx = blockIdx.x, ty = blockIdx.y;
  xcd_swz24x16(tx, ty);
  gemm_bt_bf16(A, wob, bo, out, SS, CC, CC, 2, tx, ty);
}

// ---------------------------------------------------------------------------
// Fallback (ws too small): fp32-staging GEMM (round-4 structure).
// ---------------------------------------------------------------------------
template<int AF32>
__device__ __forceinline__ void gemm_core(const void* __restrict__ Ap,
                                          const float* __restrict__ W,
                                          const float* __restrict__ bias,
                                          void* __restrict__ out,
                                          int M, int N, int K, int mode) {
  __shared__ __align__(16) bf16 As[128][32];
  __shared__ __align__(16) bf16 Ws[128][32];
  const int t = threadIdx.x, wave = t >> 6, lane = t & 63;
  const int m0 = blockIdx.y * 128, n0 = blockIdx.x * 128;
  const int wm = (wave >> 1) * 64, wn = (wave & 1) * 64;
  const int fr = lane & 15, fq = (lane >> 4) * 8;
  const int pi0 = wave * 128 + lane;
  const int pi1 = pi0 + 64;
  const int row0 = pi0 >> 2, c0 = (pi0 & 3) * 8;
  const int row1 = pi1 >> 2, c1 = (pi1 & 3) * 8;

  f32x4 raf0[2], raf1[2], rw0[2], rw1[2];
  bf16x8 rab0, rab1;

  auto issue = [&](int k0) {
    if (AF32) {
      const float* A = (const float*)Ap;
      const float* p0 = A + (size_t)(m0 + row0) * K + k0 + c0;
      raf0[0] = *(const f32x4*)p0; raf0[1] = *(const f32x4*)(p0 + 4);
      const float* p1 = A + (size_t)(m0 + row1) * K + k0 + c1;
      raf1[0] = *(const f32x4*)p1; raf1[1] = *(const f32x4*)(p1 + 4);
    } else {
      const bf16* A = (const bf16*)Ap;
      rab0 = *(const bf16x8*)(A + (size_t)(m0 + row0) * K + k0 + c0);
      rab1 = *(const bf16x8*)(A + (size_t)(m0 + row1) * K + k0 + c1);
    }
    const float* q0 = W + (size_t)(n0 + row0) * K + k0 + c0;
    rw0[0] = *(const f32x4*)q0; rw0[1] = *(const f32x4*)(q0 + 4);
    const float* q1 = W + (size_t)(n0 + row1) * K + k0 + c1;
    rw1[0] = *(const f32x4*)q1; rw1[1] = *(const f32x4*)(q1 + 4);
  };

  f32x4 acc[4][4] = {};
  issue(0);
  for (int k0 = 0; k0 < K; k0 += 32) {
    __syncthreads();
    if (AF32) {
      *(bf16x8*)&As[row0][c0] = cvt8(raf0[0], raf0[1]);
      *(bf16x8*)&As[row1][c1] = cvt8(raf1[0], raf1[1]);
    } else {
      *(bf16x8*)&As[row0][c0] = rab0;
      *(bf16x8*)&As[row1][c1] = rab1;
    }
    *(bf16x8*)&Ws[row0][c0] = cvt8(rw0[0], rw0[1]);
    *(bf16x8*)&Ws[row1][c1] = cvt8(rw1[0], rw1[1]);
    __syncthreads();
    if (k0 + 32 < K) issue(k0 + 32);
    bf16x8 a[4], b[4];
#pragma unroll
    for (int i = 0; i < 4; ++i) a[i] = *(const bf16x8*)&As[wm + i * 16 + fr][fq];
#pragma unroll
    for (int j = 0; j < 4; ++j) b[j] = *(const bf16x8*)&Ws[wn + j * 16 + fr][fq];
#pragma unroll
    for (int i = 0; i < 4; ++i)
#pragma unroll
      for (int j = 0; j < 4; ++j)
        acc[i][j] = __builtin_amdgcn_mfma_f32_16x16x32_bf16(a[i], b[j], acc[i][j], 0, 0, 0);
  }

  const int lr4 = (lane >> 4) * 4;
#pragma unroll
  for (int i = 0; i < 4; ++i) {
#pragma unroll
    for (int j = 0; j < 4; ++j) {
      const int col = n0 + wn + j * 16 + fr;
      const float bb = bias[col];
#pragma unroll
      for (int r = 0; r < 4; ++r) {
        const int row = m0 + wm + i * 16 + lr4 + r;
        const float v = acc[i][j][r] + bb;
        if (mode == 0)
          ((bf16*)out)[((size_t)(col >> 7) * M + row) * 128 + (col & 127)] = (bf16)v;
        else if (mode == 1)
          ((bf16*)out)[(size_t)col * M + row] = (bf16)v;
        else
          ((float*)out)[(size_t)row * N + col] = v;
      }
    }
  }
}

__global__ __launch_bounds__(256, 2)
void k_gemm_qkv_f(const float* __restrict__ x,
                  const float* __restrict__ wq, const float* __restrict__ wk,
                  const float* __restrict__ wv,
                  const float* __restrict__ bq, const float* __restrict__ bk,
                  const float* __restrict__ bv,
                  bf16* __restrict__ Qo, bf16* __restrict__ Ko, bf16* __restrict__ Vo) {
  const int z = blockIdx.z;
  const float* W = (z == 0) ? wq : (z == 1) ? wk : wv;
  const float* B = (z == 0) ? bq : (z == 1) ? bk : bv;
  void* O        = (z == 0) ? (void*)Qo : (z == 1) ? (void*)Ko : (void*)Vo;
  gemm_core<1>(x, W, B, O, SS, CC, CC, (z == 2) ? 1 : 0);
}

__global__ __launch_bounds__(256, 2)
void k_gemm_out_f(const bf16* __restrict__ A, const float* __restrict__ wo,
                  const float* __restrict__ bo, float* __restrict__ out) {
  gemm_core<0>(A, wo, bo, out, SS, CC, CC, 2);
}

// ---------------------------------------------------------------------------
// RMSNorm + RoPE in place on Q,K ([H][S][HD] bf16); Q gets 1/sqrt(HD)*log2e
// folded in. One wave per (s,h); lane L owns elements 2L, 2L+1.
// ---------------------------------------------------------------------------
__global__ __launch_bounds__(256)
void k_norm_rope(bf16* __restrict__ Q, bf16* __restrict__ K,
                 const float* __restrict__ rope,
                 const float* __restrict__ qw, const float* __restrict__ kw) {
  const int t = threadIdx.x, wave = t >> 6, lane = t & 63;
  const int idx = blockIdx.x * 4 + wave;
  const int s = idx / NH, h = idx % NH;
  const size_t base = ((size_t)h * SS + s) * HDIM + 2 * lane;

  bf16 q2[2], k2[2];
  *(uint32_t*)q2 = *(const uint32_t*)(Q + base);
  *(uint32_t*)k2 = *(const uint32_t*)(K + base);
  const float q0 = (float)q2[0], q1 = (float)q2[1];
  const float k0 = (float)k2[0], k1 = (float)k2[1];
  float sq = q0 * q0 + q1 * q1;
  float sk = k0 * k0 + k1 * k1;
#pragma unroll
  for (int m = 1; m < 64; m <<= 1) {
    sq += __shfl_xor(sq, m);
    sk += __shfl_xor(sk, m);
  }
  const float rq = rsqrtf(sq * (1.0f / 128.0f) + 1e-6f);
  const float rk = rsqrtf(sk * (1.0f / 128.0f) + 1e-6f);

  const float qn0 = q0 * rq * qw[2 * lane], qn1 = q1 * rq * qw[2 * lane + 1];
  const float kn0 = k0 * rk * kw[2 * lane], kn1 = k1 * rk * kw[2 * lane + 1];

  const f32x4 rp = *(const f32x4*)(rope + (size_t)s * 256 + 4 * lane);
  const float r00 = rp[0], r01 = rp[1], r10 = rp[2], r11 = rp[3];

  const float SC = 0.08838834764831845f * 1.44269504088896340f;  // 1/sqrt(128)*log2e
  const float oq0 = (r00 * qn0 + r01 * qn1) * SC;
  const float oq1 = (r10 * qn0 + r11 * qn1) * SC;
  const float ok0 = r00 * kn0 + r01 * kn1;
  const float ok1 = r10 * kn0 + r11 * kn1;

  bf16 wq2[2] = {(bf16)oq0, (bf16)oq1};
  bf16 wk2[2] = {(bf16)ok0, (bf16)ok1};
  *(uint32_t*)(Q + base) = *(uint32_t*)wq2;
  *(uint32_t*)(K + base) = *(uint32_t*)wk2;
}

// ---------------------------------------------------------------------------
// Flash attention, fixed-max softmax (exp2 domain, constant M=32).
// R7 pipelined staging (measured WIN, 524->509): Ks double-buffered, counted
// vmcnt (16/8), raw s_barrier, never vmcnt(0) in steady state. In-register P
// via swapped QK^T + kpos-permuted K staging (R5). Kept as-is.
// ---------------------------------------------------------------------------
__global__ __launch_bounds__(128, 2)
void k_attn(const bf16* __restrict__ Q, const bf16* __restrict__ Kt,
            const bf16* __restrict__ Vt, bf16* __restrict__ Out) {
  __shared__ __align__(16) bf16 Ks[2][64][128];  // dbuf: slot x d (kpos-perm) 32KB
  __shared__ __align__(16) bf16 Vs[128][64];     // d x kpos                   16KB
  const int t = threadIdx.x, wave = t >> 6, lane = t & 63;
  const int bx = blockIdx.x;               // 0..767
  const int xg = bx & 7, slot = bx >> 3;   // xcd-group, slot 0..95
  const int h = xg * 3 + (slot >> 5);      // 3 heads per xcd-group
  const int q0 = (slot & 31) * 64;
  const int fr = lane & 15, fq = (lane >> 4) * 8;
  const int g4 = lane >> 4;                // 16B-slot group 0..3
  const int wq0 = wave * 32;               // this wave's 32-row q window
  const float FM = 32.0f;  // fixed softmax max (log2 domain)

  // Q fragments for both 16-row tiles (B operand of swapped QK^T)
  bf16x8 aq[2][4];
#pragma unroll
  for (int qt = 0; qt < 2; ++qt)
#pragma unroll
    for (int kc = 0; kc < 4; ++kc)
      aq[qt][kc] = *(const bf16x8*)(
          Q + ((size_t)h * SS + q0 + wq0 + qt * 16 + fr) * HDIM + kc * 32 + fq);

  // staging lambdas: 8 x 1KB chunks per wave each (K tile 16KB, V tile 16KB)
  auto stageK = [&](int buf, int k0) {
#pragma unroll
    for (int it = 0; it < 8; ++it) {
      const int pc = wave * 8 + it;
      const int s  = pc * 4 + (lane >> 4);
      const int kp = 32 * ((s >> 4) & 1) + 8 * ((s >> 2) & 3)
                   + 4 * (s >> 5) + (s & 3);
      const int sl = (lane & 15) ^ (s & 7);
      gll16(Kt + ((size_t)h * SS + k0 + kp) * HDIM + sl * 8,
            (char*)&Ks[buf][0][0] + pc * 1024);
    }
  };
  auto stageV = [&](int k0) {
#pragma unroll
    for (int it = 0; it < 8; ++it) {
      const int pc = wave * 8 + it;
      const int d  = pc * 8 + (lane >> 3);
      const int sl = (lane & 7) ^ (d & 7);
      gll16(Vt + ((size_t)h * HDIM + d) * SS + k0 + sl * 8,
            (char*)&Vs[0][0] + pc * 1024);
    }
  };

  f32x4 oacc[2][8] = {};
  float lacc[2] = {0.f, 0.f};

  stageK(0, 0);  // prologue: K for step 0 in flight
  int cur = 0;

  for (int k0 = 0; k0 < SS; k0 += 64) {
    const bool notlast = (k0 + 64 < SS);
    stageV(k0);                       // V for THIS step (hides under QK+softmax)
    if (notlast) {
      stageK(cur ^ 1, k0 + 64);       // K for NEXT step (hides under this whole step)
      asm volatile("s_waitcnt vmcnt(16)" ::: "memory");  // K-cur landed (V+Knext in flight)
    } else {
      asm volatile("s_waitcnt vmcnt(8)" ::: "memory");   // K-cur landed (V in flight)
    }
    __builtin_amdgcn_s_barrier();
    __builtin_amdgcn_sched_barrier(0);

    // S^T tiles: mfma(A=K, B=Q) on Ks[cur]. Lane (fr,g4), reg r:
    // pv[jt][r] = P[qrow=fr][kpos = 32*(jt&1) + 8*g4 + 4*(jt>>1) + r].
    f32x4 sacc[2][4] = {};
#pragma unroll
    for (int kc = 0; kc < 4; ++kc) {
#pragma unroll
      for (int jt = 0; jt < 4; ++jt) {
        const bf16x8 b =
            *(const bf16x8*)&Ks[cur][jt * 16 + fr][((((kc << 2) + g4) ^ (fr & 7)) << 3)];
        sacc[0][jt] = __builtin_amdgcn_mfma_f32_16x16x32_bf16(b, aq[0][kc], sacc[0][jt], 0, 0, 0);
        sacc[1][jt] = __builtin_amdgcn_mfma_f32_16x16x32_bf16(b, aq[1][kc], sacc[1][jt], 0, 0, 0);
      }
    }

    // softmax in-register (no LDS) — overlaps V's in-flight loads.
    // ap[kc][j] = pv[2*(j>>2)+kc][j&3]  (kpos = 32*kc + 8*g4 + j)
    bf16x8 ap[2][2];
#pragma unroll
    for (int qt = 0; qt < 2; ++qt) {
      float pv[4][4];
      float ps = 0.f;
#pragma unroll
      for (int jt = 0; jt < 4; ++jt)
#pragma unroll
        for (int r = 0; r < 4; ++r) {
          pv[jt][r] = exp2f(sacc[qt][jt][r] - FM);
          ps += pv[jt][r];
        }
      lacc[qt] += ps;
#pragma unroll
      for (int kc = 0; kc < 2; ++kc) {
        bf16x8 a;
        a[0] = (bf16)pv[kc][0];     a[1] = (bf16)pv[kc][1];
        a[2] = (bf16)pv[kc][2];     a[3] = (bf16)pv[kc][3];
        a[4] = (bf16)pv[2 + kc][0]; a[5] = (bf16)pv[2 + kc][1];
        a[6] = (bf16)pv[2 + kc][2]; a[7] = (bf16)pv[2 + kc][3];
        ap[qt][kc] = a;
      }
    }

    if (notlast) {
      asm volatile("s_waitcnt vmcnt(8)" ::: "memory");   // V landed (Knext in flight)
    } else {
      asm volatile("s_waitcnt vmcnt(0)" ::: "memory");   // V landed (nothing else)
    }
    __builtin_amdgcn_s_barrier();
    __builtin_amdgcn_sched_barrier(0);

    // O += P V
#pragma unroll
    for (int kc = 0; kc < 2; ++kc) {
#pragma unroll
      for (int jd = 0; jd < 8; ++jd) {
        const int d = jd * 16 + fr;
        const bf16x8 b =
            *(const bf16x8*)&Vs[d][((((kc << 2) + g4) ^ (fr & 7)) << 3)];
        oacc[0][jd] = __builtin_amdgcn_mfma_f32_16x16x32_bf16(ap[0][kc], b, oacc[0][jd], 0, 0, 0);
        oacc[1][jd] = __builtin_amdgcn_mfma_f32_16x16x32_bf16(ap[1][kc], b, oacc[1][jd], 0, 0, 0);
      }
    }

    __builtin_amdgcn_s_barrier();   // WAR: all waves done reading Vs / Ks[cur]
    __builtin_amdgcn_sched_barrier(0);
    cur ^= 1;
  }

  // l[qrow=fr]: reduce partials over g4 (xor16/32), then broadcast to the
  // lanes that hold qrow = g4*4+r in the O epilogue (width-16 shfl).
#pragma unroll
  for (int qt = 0; qt < 2; ++qt) {
    float l = lacc[qt];
    l += __shfl_xor(l, 16);
    l += __shfl_xor(l, 32);
    const float linv = 1.0f / l;
#pragma unroll
    for (int r = 0; r < 4; ++r) {
      const float inv = __shfl(linv, g4 * 4 + r, 16);
      const int row = q0 + wq0 + qt * 16 + g4 * 4 + r;
#pragma unroll
      for (int jd = 0; jd < 8; ++jd) {
        const int col = h * HDIM + jd * 16 + fr;
        Out[(size_t)row * CC + col] = (bf16)(oacc[qt][jd][r] * inv);
      }
    }
  }
}

// ---------------------------------------------------------------------------
extern "C" void kernel_launch(void* const* d_in, const int* in_sizes, int n_in,
                              void* d_out, int out_size, void* d_ws, size_t ws_size,
                              hipStream_t stream) {
  const float* x    = (const float*)d_in[0];
  const float* rope = (const float*)d_in[1];
  const float* wq   = (const float*)d_in[2];
  const float* bq   = (const float*)d_in[3];
  const float* wk   = (const float*)d_in[4];
  const float* bk   = (const float*)d_in[5];
  const float* wv   = (const float*)d_in[6];
  const float* bv   = (const float*)d_in[7];
  const float* wo   = (const float*)d_in[8];
  const float* bo   = (const float*)d_in[9];
  const float* qw   = (const float*)d_in[10];
  const float* kw   = (const float*)d_in[11];

  const size_t need = (4 * NX + 4 * NW) * sizeof(bf16);
  bf16* Vt = (bf16*)d_out;  // d_out doubles as V^T scratch until final GEMM

  if (ws_size >= need) {
    bf16* xb  = (bf16*)d_ws;
    bf16* wqb = xb + NX;
    bf16* wkb = wqb + NW;
    bf16* wvb = wkb + NW;
    bf16* wob = wvb + NW;
    bf16* Qn  = wob + NW;
    bf16* Kn  = Qn + NX;
    bf16* Ao  = Kn + NX;

    k_cvt<<<dim3((unsigned)(NW / 2048), 5), 256, 0, stream>>>(x, wq, wk, wv, wo, xb);
    k_gemm_qkv_b<<<dim3(CC / 128, SS / 128, 3), 256, 0, stream>>>(
        xb, wqb, wkb, wvb, bq, bk, bv, Qn, Kn, Vt);
    k_norm_rope<<<dim3(SS * NH / 4), 256, 0, stream>>>(Qn, Kn, rope, qw, kw);
    k_attn<<<dim3((SS / 64) * NH), 128, 0, stream>>>(Qn, Kn, Vt, Ao);
    k_gemm_out_b<<<dim3(CC / 128, SS / 128), 256, 0, stream>>>(Ao, wob, bo, (float*)d_out);
  } else {
    bf16* Qn = (bf16*)d_ws;
    bf16* Kn = Qn + NX;
    bf16* Ao = Kn + NX;

    k_gemm_qkv_f<<<dim3(CC / 128, SS / 128, 3), 256, 0, stream>>>(
        x, wq, wk, wv, bq, bk, bv, Qn, Kn, Vt);
    k_norm_rope<<<dim3(SS * NH / 4), 256, 0, stream>>>(Qn, Kn, rope, qw, kw);
    k_attn<<<dim3((SS / 64) * NH), 128, 0, stream>>>(Qn, Kn, Vt, Ao);
    k_gemm_out_f<<<dim3(CC / 128, SS / 128), 256, 0, stream>>>(Ao, wo, bo, (float*)d_out);
  }
}

// Round 15
// 487.291 us; speedup vs baseline: 1.1810x; 1.0741x over previous
//
#include <hip/hip_runtime.h>
#include <cstdint>
#include <cstddef>

#define SS 2048
#define CC 3072
#define HDIM 128
#define NH 24

using bf16 = __bf16;
typedef __bf16 bf16x8 __attribute__((ext_vector_type(8)));
typedef float f32x4 __attribute__((ext_vector_type(4)));

typedef const __attribute__((address_space(1))) void* gas1_cvp;
typedef __attribute__((address_space(3))) void* las3_vp;

// async global->LDS, 16B/lane; LDS dest = wave-uniform base + lane*16
__device__ __forceinline__ void gll16(const void* g, void* l) {
  __builtin_amdgcn_global_load_lds((gas1_cvp)g, (las3_vp)l, 16, 0, 0);
}

__device__ __forceinline__ bf16x8 cvt8(f32x4 a, f32x4 b) {
  bf16x8 r;
  r[0] = (bf16)a[0]; r[1] = (bf16)a[1]; r[2] = (bf16)a[2]; r[3] = (bf16)a[3];
  r[4] = (bf16)b[0]; r[5] = (bf16)b[1]; r[6] = (bf16)b[2]; r[7] = (bf16)b[3];
  return r;
}

#define NX ((size_t)SS * CC)        // 6291456
#define NW ((size_t)CC * CC)        // 9437184
#define QSCALE (0.08838834764831845f * 1.44269504088896340f)  // 1/sqrt(128)*log2e

// ---------------------------------------------------------------------------
// fp32 -> bf16 bulk convert: z selects {x, wq, wk, wv, wo}; dst contiguous.
// ---------------------------------------------------------------------------
__global__ __launch_bounds__(256)
void k_cvt(const float* __restrict__ s0, const float* __restrict__ s1,
           const float* __restrict__ s2, const float* __restrict__ s3,
           const float* __restrict__ s4, bf16* __restrict__ dst) {
  const int z = blockIdx.y;
  const float* src = (z == 0) ? s0 : (z == 1) ? s1 : (z == 2) ? s2 : (z == 3) ? s3 : s4;
  const size_t nz = (z == 0) ? NX : NW;
  const size_t base = (z == 0) ? 0 : NX + (size_t)(z - 1) * NW;
  const size_t i = ((size_t)blockIdx.x * 256 + threadIdx.x) * 8;
  if (i < nz) {
    const f32x4 a = *(const f32x4*)(src + i);
    const f32x4 b = *(const f32x4*)(src + i + 4);
    *(bf16x8*)(dst + base + i) = cvt8(a, b);
  }
}

// ---------------------------------------------------------------------------
// Pure-bf16 bt-GEMM, BK=64, plane-split LDS. R10 config (measured 508.9us):
// natural blockIdx order (R13's XCD swizzle REVERTED: it gave each XCD all
// 24 W panels -> FETCH doubled 161->325MB, +13us).
// R14 add: mode 0 (Q/K) epilogue FUSES RMSNorm+RoPE — a mode-0 tile covers
// one head's full d-range, so row RMS = fr-shfl reduce (own 64 cols) + 1KB
// LDS partner-wave exchange; RoPE pair (2i,2i+1) = adjacent fr lanes, one
// shfl_xor(.,1). Q gets QSCALE folded; replaces the k_norm_rope dispatch +
// its 50MB Q/K round-trip. RMS now on fp32 pre-rounding values (closer to
// the fp32 reference than the old bf16 round-trip).
// mode 0: fused->out[h][s][d] bf16; mode 1: out[col][row] bf16 (V^T);
// mode 2: out[row][col] fp32 (final output).
// ---------------------------------------------------------------------------
__device__ __forceinline__ void gemm_bt_bf16(const bf16* __restrict__ A,
                                             const bf16* __restrict__ W,
                                             const float* __restrict__ bias,
                                             void* __restrict__ out,
                                             int M, int N, int K, int mode,
                                             const float* __restrict__ nw,
                                             const float* __restrict__ rope_t,
                                             float scale) {
  __shared__ __align__(16) bf16 As[2][128][32];  // [k-plane][row][32] 16KB
  __shared__ __align__(16) bf16 Ws[2][128][32];  // 16KB
  __shared__ float rs_[4][64];                   // per-wave half-row sums 1KB
  const int t = threadIdx.x, wave = t >> 6, lane = t & 63;
  const int m0 = blockIdx.y * 128, n0 = blockIdx.x * 128;
  const int wm = (wave >> 1) * 64, wn = (wave & 1) * 64;
  const int fr = lane & 15, fq = (lane >> 4) * 8;

  f32x4 acc[4][4] = {};

  for (int k0 = 0; k0 < K; k0 += 64) {
    __syncthreads();
#pragma unroll
    for (int it = 0; it < 4; ++it) {
      const int pc = wave * 4 + it;          // 1KB chunk id 0..15, wave-uniform
      const int pl = pc >> 3, rb = pc & 7;   // k-plane, 16-row block
      const int row = rb * 16 + (lane >> 2);
      const int c8 = (lane & 3) * 8;
      gll16(A + (size_t)(m0 + row) * K + k0 + pl * 32 + c8,
            (char*)&As[0][0][0] + pc * 1024);
      gll16(W + (size_t)(n0 + row) * K + k0 + pl * 32 + c8,
            (char*)&Ws[0][0][0] + pc * 1024);
    }
    __syncthreads();
#pragma unroll
    for (int c = 0; c < 2; ++c) {
      bf16x8 a[4], b[4];
#pragma unroll
      for (int i = 0; i < 4; ++i) a[i] = *(const bf16x8*)&As[c][wm + i * 16 + fr][fq];
#pragma unroll
      for (int j = 0; j < 4; ++j) b[j] = *(const bf16x8*)&Ws[c][wn + j * 16 + fr][fq];
#pragma unroll
      for (int i = 0; i < 4; ++i)
#pragma unroll
        for (int j = 0; j < 4; ++j)
          acc[i][j] = __builtin_amdgcn_mfma_f32_16x16x32_bf16(a[i], b[j], acc[i][j], 0, 0, 0);
    }
  }

  const int lr4 = (lane >> 4) * 4;

  if (mode == 0) {
    // ---- fused RMSNorm + RoPE epilogue (Q: scale=QSCALE, K: scale=1) ----
    float bcol[4], nwv[4];
#pragma unroll
    for (int j = 0; j < 4; ++j) {
      bcol[j] = bias[n0 + wn + j * 16 + fr];
      nwv[j]  = nw[wn + j * 16 + fr];
    }
    // per-row sum of squares: own-wave 64 cols via fr-shfl reduce
    float ss[4][4];
#pragma unroll
    for (int i = 0; i < 4; ++i)
#pragma unroll
      for (int r = 0; r < 4; ++r) {
        float s = 0.f;
#pragma unroll
        for (int j = 0; j < 4; ++j) {
          const float v = acc[i][j][r] + bcol[j];
          s += v * v;
        }
#pragma unroll
        for (int m = 1; m < 16; m <<= 1) s += __shfl_xor(s, m);
        ss[i][r] = s;
      }
    if (fr == 0) {
#pragma unroll
      for (int i = 0; i < 4; ++i)
#pragma unroll
        for (int r = 0; r < 4; ++r)
          rs_[wave][i * 16 + lr4 + r] = ss[i][r];
    }
    __syncthreads();

    const int hh = n0 >> 7;  // one head per column tile (128-wide heads)
#pragma unroll
    for (int i = 0; i < 4; ++i)
#pragma unroll
      for (int r = 0; r < 4; ++r) {
        const float tot = ss[i][r] + rs_[wave ^ 1][i * 16 + lr4 + r];
        const float rq = rsqrtf(tot * (1.0f / 128.0f) + 1e-6f);
        const int srow = m0 + wm + i * 16 + lr4 + r;
#pragma unroll
        for (int j = 0; j < 4; ++j) {
          const int d = wn + j * 16 + fr;
          const float vn = (acc[i][j][r] + bcol[j]) * rq * nwv[j];
          const float vp = __shfl_xor(vn, 1);  // partner d^1 value
          const f32x4 rp = *(const f32x4*)(rope_t + (size_t)srow * 256 + (d >> 1) * 4);
          const float o = ((d & 1) ? (rp[2] * vp + rp[3] * vn)
                                   : (rp[0] * vn + rp[1] * vp)) * scale;
          ((bf16*)out)[((size_t)hh * M + srow) * 128 + d] = (bf16)o;
        }
      }
    return;
  }

#pragma unroll
  for (int i = 0; i < 4; ++i) {
#pragma unroll
    for (int j = 0; j < 4; ++j) {
      const int col = n0 + wn + j * 16 + fr;
      const float bb = bias[col];
#pragma unroll
      for (int r = 0; r < 4; ++r) {
        const int row = m0 + wm + i * 16 + lr4 + r;
        const float v = acc[i][j][r] + bb;
        if (mode == 1)
          ((bf16*)out)[(size_t)col * M + row] = (bf16)v;
        else
          ((float*)out)[(size_t)row * N + col] = v;
      }
    }
  }
}

__global__ __launch_bounds__(256, 4)
void k_gemm_qkv_b(const bf16* __restrict__ xb,
                  const bf16* __restrict__ wqb, const bf16* __restrict__ wkb,
                  const bf16* __restrict__ wvb,
                  const float* __restrict__ bq, const float* __restrict__ bk,
                  const float* __restrict__ bv,
                  const float* __restrict__ rope,
                  const float* __restrict__ qw, const float* __restrict__ kw,
                  bf16* __restrict__ Qo, bf16* __restrict__ Ko, bf16* __restrict__ Vo) {
  const int z = blockIdx.z;
  if (z == 0)
    gemm_bt_bf16(xb, wqb, bq, Qo, SS, CC, CC, 0, qw, rope, QSCALE);
  else if (z == 1)
    gemm_bt_bf16(xb, wkb, bk, Ko, SS, CC, CC, 0, kw, rope, 1.0f);
  else
    gemm_bt_bf16(xb, wvb, bv, Vo, SS, CC, CC, 1, nullptr, nullptr, 1.0f);
}

__global__ __launch_bounds__(256, 4)
void k_gemm_out_b(const bf16* __restrict__ A, const bf16* __restrict__ wob,
                  const float* __restrict__ bo, float* __restrict__ out) {
  gemm_bt_bf16(A, wob, bo, out, SS, CC, CC, 2, nullptr, nullptr, 1.0f);
}

// ---------------------------------------------------------------------------
// Fallback (ws too small): fp32-staging GEMM (round-4 structure).
// ---------------------------------------------------------------------------
template<int AF32>
__device__ __forceinline__ void gemm_core(const void* __restrict__ Ap,
                                          const float* __restrict__ W,
                                          const float* __restrict__ bias,
                                          void* __restrict__ out,
                                          int M, int N, int K, int mode) {
  __shared__ __align__(16) bf16 As[128][32];
  __shared__ __align__(16) bf16 Ws[128][32];
  const int t = threadIdx.x, wave = t >> 6, lane = t & 63;
  const int m0 = blockIdx.y * 128, n0 = blockIdx.x * 128;
  const int wm = (wave >> 1) * 64, wn = (wave & 1) * 64;
  const int fr = lane & 15, fq = (lane >> 4) * 8;
  const int pi0 = wave * 128 + lane;
  const int pi1 = pi0 + 64;
  const int row0 = pi0 >> 2, c0 = (pi0 & 3) * 8;
  const int row1 = pi1 >> 2, c1 = (pi1 & 3) * 8;

  f32x4 raf0[2], raf1[2], rw0[2], rw1[2];
  bf16x8 rab0, rab1;

  auto issue = [&](int k0) {
    if (AF32) {
      const float* A = (const float*)Ap;
      const float* p0 = A + (size_t)(m0 + row0) * K + k0 + c0;
      raf0[0] = *(const f32x4*)p0; raf0[1] = *(const f32x4*)(p0 + 4);
      const float* p1 = A + (size_t)(m0 + row1) * K + k0 + c1;
      raf1[0] = *(const f32x4*)p1; raf1[1] = *(const f32x4*)(p1 + 4);
    } else {
      const bf16* A = (const bf16*)Ap;
      rab0 = *(const bf16x8*)(A + (size_t)(m0 + row0) * K + k0 + c0);
      rab1 = *(const bf16x8*)(A + (size_t)(m0 + row1) * K + k0 + c1);
    }
    const float* q0 = W + (size_t)(n0 + row0) * K + k0 + c0;
    rw0[0] = *(const f32x4*)q0; rw0[1] = *(const f32x4*)(q0 + 4);
    const float* q1 = W + (size_t)(n0 + row1) * K + k0 + c1;
    rw1[0] = *(const f32x4*)q1; rw1[1] = *(const f32x4*)(q1 + 4);
  };

  f32x4 acc[4][4] = {};
  issue(0);
  for (int k0 = 0; k0 < K; k0 += 32) {
    __syncthreads();
    if (AF32) {
      *(bf16x8*)&As[row0][c0] = cvt8(raf0[0], raf0[1]);
      *(bf16x8*)&As[row1][c1] = cvt8(raf1[0], raf1[1]);
    } else {
      *(bf16x8*)&As[row0][c0] = rab0;
      *(bf16x8*)&As[row1][c1] = rab1;
    }
    *(bf16x8*)&Ws[row0][c0] = cvt8(rw0[0], rw0[1]);
    *(bf16x8*)&Ws[row1][c1] = cvt8(rw1[0], rw1[1]);
    __syncthreads();
    if (k0 + 32 < K) issue(k0 + 32);
    bf16x8 a[4], b[4];
#pragma unroll
    for (int i = 0; i < 4; ++i) a[i] = *(const bf16x8*)&As[wm + i * 16 + fr][fq];
#pragma unroll
    for (int j = 0; j < 4; ++j) b[j] = *(const bf16x8*)&Ws[wn + j * 16 + fr][fq];
#pragma unroll
    for (int i = 0; i < 4; ++i)
#pragma unroll
      for (int j = 0; j < 4; ++j)
        acc[i][j] = __builtin_amdgcn_mfma_f32_16x16x32_bf16(a[i], b[j], acc[i][j], 0, 0, 0);
  }

  const int lr4 = (lane >> 4) * 4;
#pragma unroll
  for (int i = 0; i < 4; ++i) {
#pragma unroll
    for (int j = 0; j < 4; ++j) {
      const int col = n0 + wn + j * 16 + fr;
      const float bb = bias[col];
#pragma unroll
      for (int r = 0; r < 4; ++r) {
        const int row = m0 + wm + i * 16 + lr4 + r;
        const float v = acc[i][j][r] + bb;
        if (mode == 0)
          ((bf16*)out)[((size_t)(col >> 7) * M + row) * 128 + (col & 127)] = (bf16)v;
        else if (mode == 1)
          ((bf16*)out)[(size_t)col * M + row] = (bf16)v;
        else
          ((float*)out)[(size_t)row * N + col] = v;
      }
    }
  }
}

__global__ __launch_bounds__(256, 2)
void k_gemm_qkv_f(const float* __restrict__ x,
                  const float* __restrict__ wq, const float* __restrict__ wk,
                  const float* __restrict__ wv,
                  const float* __restrict__ bq, const float* __restrict__ bk,
                  const float* __restrict__ bv,
                  bf16* __restrict__ Qo, bf16* __restrict__ Ko, bf16* __restrict__ Vo) {
  const int z = blockIdx.z;
  const float* W = (z == 0) ? wq : (z == 1) ? wk : wv;
  const float* B = (z == 0) ? bq : (z == 1) ? bk : bv;
  void* O        = (z == 0) ? (void*)Qo : (z == 1) ? (void*)Ko : (void*)Vo;
  gemm_core<1>(x, W, B, O, SS, CC, CC, (z == 2) ? 1 : 0);
}

__global__ __launch_bounds__(256, 2)
void k_gemm_out_f(const bf16* __restrict__ A, const float* __restrict__ wo,
                  const float* __restrict__ bo, float* __restrict__ out) {
  gemm_core<0>(A, wo, bo, out, SS, CC, CC, 2);
}

// ---------------------------------------------------------------------------
// RMSNorm + RoPE in place on Q,K — used only by the fallback path now.
// ---------------------------------------------------------------------------
__global__ __launch_bounds__(256)
void k_norm_rope(bf16* __restrict__ Q, bf16* __restrict__ K,
                 const float* __restrict__ rope,
                 const float* __restrict__ qw, const float* __restrict__ kw) {
  const int t = threadIdx.x, wave = t >> 6, lane = t & 63;
  const int idx = blockIdx.x * 4 + wave;
  const int s = idx / NH, h = idx % NH;
  const size_t base = ((size_t)h * SS + s) * HDIM + 2 * lane;

  bf16 q2[2], k2[2];
  *(uint32_t*)q2 = *(const uint32_t*)(Q + base);
  *(uint32_t*)k2 = *(const uint32_t*)(K + base);
  const float q0 = (float)q2[0], q1 = (float)q2[1];
  const float k0 = (float)k2[0], k1 = (float)k2[1];
  float sq = q0 * q0 + q1 * q1;
  float sk = k0 * k0 + k1 * k1;
#pragma unroll
  for (int m = 1; m < 64; m <<= 1) {
    sq += __shfl_xor(sq, m);
    sk += __shfl_xor(sk, m);
  }
  const float rq = rsqrtf(sq * (1.0f / 128.0f) + 1e-6f);
  const float rk = rsqrtf(sk * (1.0f / 128.0f) + 1e-6f);

  const float qn0 = q0 * rq * qw[2 * lane], qn1 = q1 * rq * qw[2 * lane + 1];
  const float kn0 = k0 * rk * kw[2 * lane], kn1 = k1 * rk * kw[2 * lane + 1];

  const f32x4 rp = *(const f32x4*)(rope + (size_t)s * 256 + 4 * lane);
  const float r00 = rp[0], r01 = rp[1], r10 = rp[2], r11 = rp[3];

  const float oq0 = (r00 * qn0 + r01 * qn1) * QSCALE;
  const float oq1 = (r10 * qn0 + r11 * qn1) * QSCALE;
  const float ok0 = r00 * kn0 + r01 * kn1;
  const float ok1 = r10 * kn0 + r11 * kn1;

  bf16 wq2[2] = {(bf16)oq0, (bf16)oq1};
  bf16 wk2[2] = {(bf16)ok0, (bf16)ok1};
  *(uint32_t*)(Q + base) = *(uint32_t*)wq2;
  *(uint32_t*)(K + base) = *(uint32_t*)wk2;
}

// ---------------------------------------------------------------------------
// Flash attention, fixed-max softmax (exp2 domain, constant M=32).
// R7 pipelined staging (measured WIN, 524->509): Ks double-buffered, counted
// vmcnt (16/8), raw s_barrier, never vmcnt(0) in steady state. In-register P
// via swapped QK^T + kpos-permuted K staging (R5). Kept as-is.
// ---------------------------------------------------------------------------
__global__ __launch_bounds__(128, 2)
void k_attn(const bf16* __restrict__ Q, const bf16* __restrict__ Kt,
            const bf16* __restrict__ Vt, bf16* __restrict__ Out) {
  __shared__ __align__(16) bf16 Ks[2][64][128];  // dbuf: slot x d (kpos-perm) 32KB
  __shared__ __align__(16) bf16 Vs[128][64];     // d x kpos                   16KB
  const int t = threadIdx.x, wave = t >> 6, lane = t & 63;
  const int bx = blockIdx.x;               // 0..767
  const int xg = bx & 7, slot = bx >> 3;   // xcd-group, slot 0..95
  const int h = xg * 3 + (slot >> 5);      // 3 heads per xcd-group
  const int q0 = (slot & 31) * 64;
  const int fr = lane & 15, fq = (lane >> 4) * 8;
  const int g4 = lane >> 4;                // 16B-slot group 0..3
  const int wq0 = wave * 32;               // this wave's 32-row q window
  const float FM = 32.0f;  // fixed softmax max (log2 domain)

  // Q fragments for both 16-row tiles (B operand of swapped QK^T)
  bf16x8 aq[2][4];
#pragma unroll
  for (int qt = 0; qt < 2; ++qt)
#pragma unroll
    for (int kc = 0; kc < 4; ++kc)
      aq[qt][kc] = *(const bf16x8*)(
          Q + ((size_t)h * SS + q0 + wq0 + qt * 16 + fr) * HDIM + kc * 32 + fq);

  // staging lambdas: 8 x 1KB chunks per wave each (K tile 16KB, V tile 16KB)
  auto stageK = [&](int buf, int k0) {
#pragma unroll
    for (int it = 0; it < 8; ++it) {
      const int pc = wave * 8 + it;
      const int s  = pc * 4 + (lane >> 4);
      const int kp = 32 * ((s >> 4) & 1) + 8 * ((s >> 2) & 3)
                   + 4 * (s >> 5) + (s & 3);
      const int sl = (lane & 15) ^ (s & 7);
      gll16(Kt + ((size_t)h * SS + k0 + kp) * HDIM + sl * 8,
            (char*)&Ks[buf][0][0] + pc * 1024);
    }
  };
  auto stageV = [&](int k0) {
#pragma unroll
    for (int it = 0; it < 8; ++it) {
      const int pc = wave * 8 + it;
      const int d  = pc * 8 + (lane >> 3);
      const int sl = (lane & 7) ^ (d & 7);
      gll16(Vt + ((size_t)h * HDIM + d) * SS + k0 + sl * 8,
            (char*)&Vs[0][0] + pc * 1024);
    }
  };

  f32x4 oacc[2][8] = {};
  float lacc[2] = {0.f, 0.f};

  stageK(0, 0);  // prologue: K for step 0 in flight
  int cur = 0;

  for (int k0 = 0; k0 < SS; k0 += 64) {
    const bool notlast = (k0 + 64 < SS);
    stageV(k0);                       // V for THIS step (hides under QK+softmax)
    if (notlast) {
      stageK(cur ^ 1, k0 + 64);       // K for NEXT step (hides under this whole step)
      asm volatile("s_waitcnt vmcnt(16)" ::: "memory");  // K-cur landed (V+Knext in flight)
    } else {
      asm volatile("s_waitcnt vmcnt(8)" ::: "memory");   // K-cur landed (V in flight)
    }
    __builtin_amdgcn_s_barrier();
    __builtin_amdgcn_sched_barrier(0);

    // S^T tiles: mfma(A=K, B=Q) on Ks[cur]. Lane (fr,g4), reg r:
    // pv[jt][r] = P[qrow=fr][kpos = 32*(jt&1) + 8*g4 + 4*(jt>>1) + r].
    f32x4 sacc[2][4] = {};
#pragma unroll
    for (int kc = 0; kc < 4; ++kc) {
#pragma unroll
      for (int jt = 0; jt < 4; ++jt) {
        const bf16x8 b =
            *(const bf16x8*)&Ks[cur][jt * 16 + fr][((((kc << 2) + g4) ^ (fr & 7)) << 3)];
        sacc[0][jt] = __builtin_amdgcn_mfma_f32_16x16x32_bf16(b, aq[0][kc], sacc[0][jt], 0, 0, 0);
        sacc[1][jt] = __builtin_amdgcn_mfma_f32_16x16x32_bf16(b, aq[1][kc], sacc[1][jt], 0, 0, 0);
      }
    }

    // softmax in-register (no LDS) — overlaps V's in-flight loads.
    // ap[kc][j] = pv[2*(j>>2)+kc][j&3]  (kpos = 32*kc + 8*g4 + j)
    bf16x8 ap[2][2];
#pragma unroll
    for (int qt = 0; qt < 2; ++qt) {
      float pv[4][4];
      float ps = 0.f;
#pragma unroll
      for (int jt = 0; jt < 4; ++jt)
#pragma unroll
        for (int r = 0; r < 4; ++r) {
          pv[jt][r] = exp2f(sacc[qt][jt][r] - FM);
          ps += pv[jt][r];
        }
      lacc[qt] += ps;
#pragma unroll
      for (int kc = 0; kc < 2; ++kc) {
        bf16x8 a;
        a[0] = (bf16)pv[kc][0];     a[1] = (bf16)pv[kc][1];
        a[2] = (bf16)pv[kc][2];     a[3] = (bf16)pv[kc][3];
        a[4] = (bf16)pv[2 + kc][0]; a[5] = (bf16)pv[2 + kc][1];
        a[6] = (bf16)pv[2 + kc][2]; a[7] = (bf16)pv[2 + kc][3];
        ap[qt][kc] = a;
      }
    }

    if (notlast) {
      asm volatile("s_waitcnt vmcnt(8)" ::: "memory");   // V landed (Knext in flight)
    } else {
      asm volatile("s_waitcnt vmcnt(0)" ::: "memory");   // V landed (nothing else)
    }
    __builtin_amdgcn_s_barrier();
    __builtin_amdgcn_sched_barrier(0);

    // O += P V
#pragma unroll
    for (int kc = 0; kc < 2; ++kc) {
#pragma unroll
      for (int jd = 0; jd < 8; ++jd) {
        const int d = jd * 16 + fr;
        const bf16x8 b =
            *(const bf16x8*)&Vs[d][((((kc << 2) + g4) ^ (fr & 7)) << 3)];
        oacc[0][jd] = __builtin_amdgcn_mfma_f32_16x16x32_bf16(ap[0][kc], b, oacc[0][jd], 0, 0, 0);
        oacc[1][jd] = __builtin_amdgcn_mfma_f32_16x16x32_bf16(ap[1][kc], b, oacc[1][jd], 0, 0, 0);
      }
    }

    __builtin_amdgcn_s_barrier();   // WAR: all waves done reading Vs / Ks[cur]
    __builtin_amdgcn_sched_barrier(0);
    cur ^= 1;
  }

  // l[qrow=fr]: reduce partials over g4 (xor16/32), then broadcast to the
  // lanes that hold qrow = g4*4+r in the O epilogue (width-16 shfl).
#pragma unroll
  for (int qt = 0; qt < 2; ++qt) {
    float l = lacc[qt];
    l += __shfl_xor(l, 16);
    l += __shfl_xor(l, 32);
    const float linv = 1.0f / l;
#pragma unroll
    for (int r = 0; r < 4; ++r) {
      const float inv = __shfl(linv, g4 * 4 + r, 16);
      const int row = q0 + wq0 + qt * 16 + g4 * 4 + r;
#pragma unroll
      for (int jd = 0; jd < 8; ++jd) {
        const int col = h * HDIM + jd * 16 + fr;
        Out[(size_t)row * CC + col] = (bf16)(oacc[qt][jd][r] * inv);
      }
    }
  }
}

// ---------------------------------------------------------------------------
extern "C" void kernel_launch(void* const* d_in, const int* in_sizes, int n_in,
                              void* d_out, int out_size, void* d_ws, size_t ws_size,
                              hipStream_t stream) {
  const float* x    = (const float*)d_in[0];
  const float* rope = (const float*)d_in[1];
  const float* wq   = (const float*)d_in[2];
  const float* bq   = (const float*)d_in[3];
  const float* wk   = (const float*)d_in[4];
  const float* bk   = (const float*)d_in[5];
  const float* wv   = (const float*)d_in[6];
  const float* bv   = (const float*)d_in[7];
  const float* wo   = (const float*)d_in[8];
  const float* bo   = (const float*)d_in[9];
  const float* qw   = (const float*)d_in[10];
  const float* kw   = (const float*)d_in[11];

  const size_t need = (4 * NX + 4 * NW) * sizeof(bf16);
  bf16* Vt = (bf16*)d_out;  // d_out doubles as V^T scratch until final GEMM

  if (ws_size >= need) {
    bf16* xb  = (bf16*)d_ws;
    bf16* wqb = xb + NX;
    bf16* wkb = wqb + NW;
    bf16* wvb = wkb + NW;
    bf16* wob = wvb + NW;
    bf16* Qn  = wob + NW;
    bf16* Kn  = Qn + NX;
    bf16* Ao  = Kn + NX;

    k_cvt<<<dim3((unsigned)(NW / 2048), 5), 256, 0, stream>>>(x, wq, wk, wv, wo, xb);
    k_gemm_qkv_b<<<dim3(CC / 128, SS / 128, 3), 256, 0, stream>>>(
        xb, wqb, wkb, wvb, bq, bk, bv, rope, qw, kw, Qn, Kn, Vt);
    k_attn<<<dim3((SS / 64) * NH), 128, 0, stream>>>(Qn, Kn, Vt, Ao);
    k_gemm_out_b<<<dim3(CC / 128, SS / 128), 256, 0, stream>>>(Ao, wob, bo, (float*)d_out);
  } else {
    bf16* Qn = (bf16*)d_ws;
    bf16* Kn = Qn + NX;
    bf16* Ao = Kn + NX;

    k_gemm_qkv_f<<<dim3(CC / 128, SS / 128, 3), 256, 0, stream>>>(
        x, wq, wk, wv, bq, bk, bv, Qn, Kn, Vt);
    k_norm_rope<<<dim3(SS * NH / 4), 256, 0, stream>>>(Qn, Kn, rope, qw, kw);
    k_attn<<<dim3((SS / 64) * NH), 128, 0, stream>>>(Qn, Kn, Vt, Ao);
    k_gemm_out_f<<<dim3(CC / 128, SS / 128), 256, 0, stream>>>(Ao, wo, bo, (float*)d_out);
  }
}